// Round 9
// baseline (163.335 us; speedup 1.0000x reference)
//
#include <hip/hip_runtime.h>

#define NN 50000
#define NE 800000
#define ND 1000000
#define DH 128
#define DO 64

#define CB ((NE + 255) / 256)          // 3125 count blocks
#define WTB 96                         // (128*128 + 128*64)/256 transpose blocks

typedef _Float16 h16;
typedef h16 h16x2 __attribute__((ext_vector_type(2)));
typedef h16 h16x4 __attribute__((ext_vector_type(4)));
typedef h16 h16x8 __attribute__((ext_vector_type(8)));
typedef float f32x4 __attribute__((ext_vector_type(4)));

// K1: degree count (atomic, rank capture) || W transpose+fp16 convert. No LDS.
__global__ void k_count_wt(const int* __restrict__ dst, int* __restrict__ degi,
                           int* __restrict__ rank,
                           const float* __restrict__ Wi, const float* __restrict__ Wo,
                           h16* __restrict__ WiT, h16* __restrict__ WoT) {
    if (blockIdx.x < CB) {
        int i = blockIdx.x * 256 + threadIdx.x;
        if (i < NE) rank[i] = atomicAdd(&degi[dst[i]], 1);
    } else {
        int t = (blockIdx.x - CB) * 256 + threadIdx.x;
        if (t < 128 * 128) {            // WiT[n][k] = Wi[k][n]
            int k = t >> 7, n = t & 127;
            WiT[n * 128 + k] = (h16)Wi[t];
        } else {                        // WoT[n][k] = Wo[k][n]
            int t2 = t - 128 * 128;     // < 8192
            int k = t2 >> 6, n = t2 & 63;
            WoT[n * 128 + k] = (h16)Wo[t2];
        }
    }
}

// Single-kernel CSR offset alloc + dinv: block-local LDS scan, one atomic
// block-base bump (degi[NN] is the global counter, zeroed with degi).
// Buckets are not ordered across blocks -- aggregators use off[n]+degi[n].
__global__ __launch_bounds__(1024) void k_scandinv(int* __restrict__ degi,
                                                   int* __restrict__ off,
                                                   float* __restrict__ dinv) {
    int b = blockIdx.x, t = threadIdx.x;
    int i = b * 1024 + t;
    int v = (i < NN) ? degi[i] : 0;
    __shared__ int s[1024];
    __shared__ int sbase;
    s[t] = v;
    __syncthreads();
#pragma unroll
    for (int d = 1; d < 1024; d <<= 1) {
        int add = (t >= d) ? s[t - d] : 0;
        __syncthreads();
        s[t] += add;
        __syncthreads();
    }
    if (t == 1023) sbase = atomicAdd(&degi[NN], s[1023]);
    __syncthreads();
    if (i < NN) {
        off[i] = sbase + s[t] - v;   // block-local exclusive + dynamic base
        dinv[i] = rsqrtf((float)v + 1.0f);  // +1 self-loop
    }
}

// pure scatter, no atomics (rank captured in k_count_wt)
__global__ void k_fill(const int* __restrict__ src, const int* __restrict__ dst,
                       const int* __restrict__ off, const int* __restrict__ rank,
                       int* __restrict__ csrc) {
    int i = blockIdx.x * blockDim.x + threadIdx.x;
    if (i < NE) csrc[off[dst[i]] + rank[i]] = src[i];
}

// MFMA GEMM: out[row][:] = fp16( (A[row][:] @ W) * dinv[row] )
// BM=64 rows/block, 256 thr (4 waves, each wave: 16 rows x BN cols).
template <int BN, bool AF32>
__global__ __launch_bounds__(256) void k_gemm_mfma(
    const void* __restrict__ Ain, const h16* __restrict__ WT,
    const float* __restrict__ dinv, h16* __restrict__ out) {
    __shared__ h16x8 sXv[64 * 16];
    __shared__ h16x8 sWv[BN * 16];
    char* sX = (char*)sXv;
    char* sW = (char*)sWv;
    const int tid = threadIdx.x;
    const int row0 = blockIdx.x * 64;

    // ---- stage A: 1024 16B chunks (row, kb), swizzle byte ^= (row&7)<<4 ----
#pragma unroll
    for (int i = 0; i < 4; ++i) {
        int c = tid + i * 256;
        int row = c >> 4, kb = c & 15;
        int gr = row0 + row;
        h16x8 v = {};
        if (gr < NN) {
            if (AF32) {
                const float* src = (const float*)Ain + (size_t)gr * 128 + kb * 8;
                float4 u0 = *(const float4*)src;
                float4 u1 = *(const float4*)(src + 4);
                v[0] = (h16)u0.x; v[1] = (h16)u0.y; v[2] = (h16)u0.z; v[3] = (h16)u0.w;
                v[4] = (h16)u1.x; v[5] = (h16)u1.y; v[6] = (h16)u1.z; v[7] = (h16)u1.w;
            } else {
                v = *(const h16x8*)((const h16*)Ain + (size_t)gr * 128 + kb * 8);
            }
        }
        *(h16x8*)(sX + row * 256 + ((kb * 16) ^ ((row & 7) << 4))) = v;
    }
    // ---- stage WT: BN*16 chunks ----
#pragma unroll
    for (int i = 0; i < BN / 16; ++i) {
        int c = tid + i * 256;
        int n = c >> 4, kb = c & 15;
        h16x8 v = *(const h16x8*)&WT[(size_t)n * 128 + kb * 8];
        *(h16x8*)(sW + n * 256 + ((kb * 16) ^ ((n & 7) << 4))) = v;
    }
    __syncthreads();

    const int lane = tid & 63, wv = tid >> 6;
    const int g = lane >> 4, l15 = lane & 15;
    const int r = wv * 16 + l15;       // A row (local)
    f32x4 acc[BN / 16];
#pragma unroll
    for (int ct = 0; ct < BN / 16; ++ct) acc[ct] = (f32x4){0.f, 0.f, 0.f, 0.f};

#pragma unroll
    for (int t = 0; t < 4; ++t) {
        int kb2 = t * 64 + g * 16;     // byte offset of k-base within row
        h16x8 a = *(const h16x8*)(sX + r * 256 + (kb2 ^ ((r & 7) << 4)));
#pragma unroll
        for (int ct = 0; ct < BN / 16; ++ct) {
            int n = ct * 16 + l15;
            h16x8 b = *(const h16x8*)(sW + n * 256 + (kb2 ^ ((n & 7) << 4)));
            acc[ct] = __builtin_amdgcn_mfma_f32_16x16x32_f16(a, b, acc[ct], 0, 0, 0);
        }
    }

#pragma unroll
    for (int j = 0; j < 4; ++j) {
        int row = row0 + wv * 16 + g * 4 + j;
        if (row < NN) {
            float dv = dinv[row];
#pragma unroll
            for (int ct = 0; ct < BN / 16; ++ct)
                out[(size_t)row * BN + ct * 16 + l15] = (h16)(acc[ct][j] * dv);
        }
    }
}

// z1[n] = fp16(relu(dinv[n]*(sum h1[src] + h1[n]) + b))
// 32-lane group per node (h16x4/lane), 2 nodes/wave, no cross-lane reduce.
__global__ __launch_bounds__(256) void k_agg128(
    const h16x4* __restrict__ hs, const float* __restrict__ dinv,
    const int* __restrict__ off, const int* __restrict__ degi,
    const int* __restrict__ csrc,
    const float* __restrict__ bias, h16x4* __restrict__ z) {
    int node = blockIdx.x * 8 + (threadIdx.x >> 5);
    if (node >= NN) return;
    int col = threadIdx.x & 31;              // row = 32 h16x4
    int s = off[node], e = s + degi[node];
    float a0 = 0.f, a1 = 0.f, a2 = 0.f, a3 = 0.f;
    int j = s;
    for (; j + 8 <= e; j += 8) {
        int i0 = csrc[j],     i1 = csrc[j + 1], i2 = csrc[j + 2], i3 = csrc[j + 3];
        int i4 = csrc[j + 4], i5 = csrc[j + 5], i6 = csrc[j + 6], i7 = csrc[j + 7];
        h16x4 v0 = hs[(size_t)i0 * 32 + col];
        h16x4 v1 = hs[(size_t)i1 * 32 + col];
        h16x4 v2 = hs[(size_t)i2 * 32 + col];
        h16x4 v3 = hs[(size_t)i3 * 32 + col];
        h16x4 v4 = hs[(size_t)i4 * 32 + col];
        h16x4 v5 = hs[(size_t)i5 * 32 + col];
        h16x4 v6 = hs[(size_t)i6 * 32 + col];
        h16x4 v7 = hs[(size_t)i7 * 32 + col];
        a0 += ((float)v0.x + (float)v1.x + (float)v2.x + (float)v3.x) +
              ((float)v4.x + (float)v5.x + (float)v6.x + (float)v7.x);
        a1 += ((float)v0.y + (float)v1.y + (float)v2.y + (float)v3.y) +
              ((float)v4.y + (float)v5.y + (float)v6.y + (float)v7.y);
        a2 += ((float)v0.z + (float)v1.z + (float)v2.z + (float)v3.z) +
              ((float)v4.z + (float)v5.z + (float)v6.z + (float)v7.z);
        a3 += ((float)v0.w + (float)v1.w + (float)v2.w + (float)v3.w) +
              ((float)v4.w + (float)v5.w + (float)v6.w + (float)v7.w);
    }
    for (; j < e; ++j) {
        h16x4 v = hs[(size_t)csrc[j] * 32 + col];
        a0 += (float)v.x; a1 += (float)v.y; a2 += (float)v.z; a3 += (float)v.w;
    }
    h16x4 vs = hs[(size_t)node * 32 + col];  // self loop
    a0 += (float)vs.x; a1 += (float)vs.y; a2 += (float)vs.z; a3 += (float)vs.w;
    float dv = dinv[node];
    float4 bb = ((const float4*)bias)[col];
    float r0 = dv * a0 + bb.x, r1 = dv * a1 + bb.y;
    float r2 = dv * a2 + bb.z, r3 = dv * a3 + bb.w;
    h16x4 o;
    o.x = (h16)(r0 > 0.f ? r0 : 0.f); o.y = (h16)(r1 > 0.f ? r1 : 0.f);
    o.z = (h16)(r2 > 0.f ? r2 : 0.f); o.w = (h16)(r3 > 0.f ? r3 : 0.f);
    z[(size_t)node * 32 + col] = o;
}

// z2 planes: za[n][0..31], zb[n][32..63] = fp16(relu(...))
// 16-lane group per node (h16x4/lane), 4 nodes/wave.
__global__ __launch_bounds__(256) void k_agg64(
    const h16x4* __restrict__ hs, const float* __restrict__ dinv,
    const int* __restrict__ off, const int* __restrict__ degi,
    const int* __restrict__ csrc,
    const float* __restrict__ bias, h16* __restrict__ za, h16* __restrict__ zb) {
    int node = blockIdx.x * 16 + (threadIdx.x >> 4);
    if (node >= NN) return;
    int col = threadIdx.x & 15;              // row = 16 h16x4
    int s = off[node], e = s + degi[node];
    float a0 = 0.f, a1 = 0.f, a2 = 0.f, a3 = 0.f;
    int j = s;
    for (; j + 8 <= e; j += 8) {
        int i0 = csrc[j],     i1 = csrc[j + 1], i2 = csrc[j + 2], i3 = csrc[j + 3];
        int i4 = csrc[j + 4], i5 = csrc[j + 5], i6 = csrc[j + 6], i7 = csrc[j + 7];
        h16x4 v0 = hs[(size_t)i0 * 16 + col];
        h16x4 v1 = hs[(size_t)i1 * 16 + col];
        h16x4 v2 = hs[(size_t)i2 * 16 + col];
        h16x4 v3 = hs[(size_t)i3 * 16 + col];
        h16x4 v4 = hs[(size_t)i4 * 16 + col];
        h16x4 v5 = hs[(size_t)i5 * 16 + col];
        h16x4 v6 = hs[(size_t)i6 * 16 + col];
        h16x4 v7 = hs[(size_t)i7 * 16 + col];
        a0 += ((float)v0.x + (float)v1.x + (float)v2.x + (float)v3.x) +
              ((float)v4.x + (float)v5.x + (float)v6.x + (float)v7.x);
        a1 += ((float)v0.y + (float)v1.y + (float)v2.y + (float)v3.y) +
              ((float)v4.y + (float)v5.y + (float)v6.y + (float)v7.y);
        a2 += ((float)v0.z + (float)v1.z + (float)v2.z + (float)v3.z) +
              ((float)v4.z + (float)v5.z + (float)v6.z + (float)v7.z);
        a3 += ((float)v0.w + (float)v1.w + (float)v2.w + (float)v3.w) +
              ((float)v4.w + (float)v5.w + (float)v6.w + (float)v7.w);
    }
    for (; j < e; ++j) {
        h16x4 v = hs[(size_t)csrc[j] * 16 + col];
        a0 += (float)v.x; a1 += (float)v.y; a2 += (float)v.z; a3 += (float)v.w;
    }
    h16x4 vs = hs[(size_t)node * 16 + col];  // self loop
    a0 += (float)vs.x; a1 += (float)vs.y; a2 += (float)vs.z; a3 += (float)vs.w;
    float dv = dinv[node];
    float4 bb = ((const float4*)bias)[col];
    float r0 = dv * a0 + bb.x, r1 = dv * a1 + bb.y;
    float r2 = dv * a2 + bb.z, r3 = dv * a3 + bb.w;
    h16x4 o;
    o.x = (h16)(r0 > 0.f ? r0 : 0.f); o.y = (h16)(r1 > 0.f ? r1 : 0.f);
    o.z = (h16)(r2 > 0.f ? r2 : 0.f); o.w = (h16)(r3 > 0.f ? r3 : 0.f);
    h16* zp = (col < 8) ? za : zb;
    *(h16x4*)&zp[(size_t)node * 32 + (col & 7) * 4] = o;
}

// dec pass over one 32-col plane (3.2 MB -> L2-resident).
// 4-lane groups, h16x8 (16B) loads, 4 pairs/group, 2-step shuffle reduce.
template <int PASS>
__global__ __launch_bounds__(256) void k_dec_pass(const h16* __restrict__ zp,
                                                  const int* __restrict__ eli,
                                                  float* __restrict__ out) {
    int g = blockIdx.x * 64 + (threadIdx.x >> 2);
    int p0 = g * 4;
    if (p0 >= ND) return;
    int sub = threadIdx.x & 3;
    float v[4];
#pragma unroll
    for (int q = 0; q < 4; ++q) {
        int ia = eli[p0 + q];
        int ib = eli[ND + p0 + q];
        h16x8 va = *(const h16x8*)&zp[(size_t)ia * 32 + sub * 8];
        h16x8 vb = *(const h16x8*)&zp[(size_t)ib * 32 + sub * 8];
        float acc = 0.f;
#pragma unroll
        for (int k = 0; k < 8; ++k) acc += (float)va[k] * (float)vb[k];
        v[q] = acc;
    }
#pragma unroll
    for (int o = 1; o < 4; o <<= 1) {
#pragma unroll
        for (int q = 0; q < 4; ++q) v[q] += __shfl_xor(v[q], o);
    }
    if (sub == 0) {
        float4 r = make_float4(v[0], v[1], v[2], v[3]);
        if (PASS) {
            float4 prev = *(const float4*)&out[p0];
            r.x += prev.x; r.y += prev.y; r.z += prev.z; r.w += prev.w;
        }
        *(float4*)&out[p0] = r;
    }
}

extern "C" void kernel_launch(void* const* d_in, const int* in_sizes, int n_in,
                              void* d_out, int out_size, void* d_ws, size_t ws_size,
                              hipStream_t stream) {
    const float* x  = (const float*)d_in[0];
    const float* Wi = (const float*)d_in[1];
    const float* bi = (const float*)d_in[2];
    const float* Wo = (const float*)d_in[3];
    const float* bo = (const float*)d_in[4];
    const int* ei   = (const int*)d_in[5];
    const int* eli  = (const int*)d_in[6];
    float* out = (float*)d_out;

    char* ws = (char*)d_ws;
    size_t o = 0;
    auto alloc = [&](size_t bytes) -> char* {
        char* p = ws + o;
        o = (o + bytes + 255) & ~(size_t)255;
        return p;
    };
    float* dinv = (float*)alloc(NN * 4);
    int* degi   = (int*)alloc((NN + 1) * 4);   // degi[NN] = scan base counter
    int* off    = (int*)alloc(NN * 4);
    int* rank   = (int*)alloc((size_t)NE * 4);
    int* csrc   = (int*)alloc((size_t)NE * 4);
    h16* WiT    = (h16*)alloc(128 * 128 * 2);
    h16* WoT    = (h16*)alloc(64 * 128 * 2);
    h16* h1     = (h16*)alloc((size_t)NN * DH * 2);
    h16* z1     = (h16*)alloc((size_t)NN * DH * 2);
    h16* h2     = (h16*)alloc((size_t)NN * DO * 2);
    h16* z2a    = (h16*)alloc((size_t)NN * 32 * 2);
    h16* z2b    = (h16*)alloc((size_t)NN * 32 * 2);

    const int* esrc = ei;
    const int* edst = ei + NE;

    hipMemsetAsync(degi, 0, (NN + 1) * 4, stream);
    k_count_wt<<<CB + WTB, 256, 0, stream>>>(edst, degi, rank, Wi, Wo, WiT, WoT);
    k_scandinv<<<(NN + 1023) / 1024, 1024, 0, stream>>>(degi, off, dinv);
    k_fill<<<CB, 256, 0, stream>>>(esrc, edst, off, rank, csrc);

    k_gemm_mfma<DH, true><<<(NN + 63) / 64, 256, 0, stream>>>(x, WiT, dinv, h1);
    k_agg128<<<(NN + 7) / 8, 256, 0, stream>>>((const h16x4*)h1, dinv, off, degi, csrc, bi, (h16x4*)z1);
    k_gemm_mfma<DO, false><<<(NN + 63) / 64, 256, 0, stream>>>(z1, WoT, dinv, h2);
    k_agg64<<<(NN + 15) / 16, 256, 0, stream>>>((const h16x4*)h2, dinv, off, degi, csrc, bo, z2a, z2b);

    k_dec_pass<0><<<(ND / 4 + 63) / 64, 256, 0, stream>>>(z2a, eli, out);
    k_dec_pass<1><<<(ND / 4 + 63) / 64, 256, 0, stream>>>(z2b, eli, out);
}

// Round 10
// 124.415 us; speedup vs baseline: 1.3128x; 1.3128x over previous
//
#include <hip/hip_runtime.h>

#define NN 50000
#define NE 800000
#define ND 1000000
#define DH 128
#define DO 64

#define NB 196          // buckets: bucket = dst >> 8 (256 nodes each)
#define BCAP 5120       // per-bucket capacity (mean 4096, sd ~64 -> 16 sigma)
#define P1B 196         // pass-1 edge blocks (1024 thr x 4 edges = 4096)
#define WTB1 24         // transpose blocks (1024 thr): (16384+8192)/1024

typedef _Float16 h16;
typedef h16 h16x4 __attribute__((ext_vector_type(4)));
typedef h16 h16x8 __attribute__((ext_vector_type(8)));
typedef float f32x4 __attribute__((ext_vector_type(4)));

// Pass 1: bucket edges by dst>>8 (packed src|dlow<<16) || W transpose.
__global__ __launch_bounds__(1024) void k_bucket_wt(
    const int* __restrict__ esrc, const int* __restrict__ edst,
    int* __restrict__ bpk, int* __restrict__ bcur,
    const float* __restrict__ Wi, const float* __restrict__ Wo,
    h16* __restrict__ WiT, h16* __restrict__ WoT) {
    if (blockIdx.x < P1B) {
        __shared__ int hist[NB], gbase[NB], lcur[NB];
        int t = threadIdx.x;
        if (t < NB) { hist[t] = 0; lcur[t] = 0; }
        __syncthreads();
        int base = blockIdx.x * 4096;
        int s[4], b[4], pk[4];
#pragma unroll
        for (int i = 0; i < 4; ++i) {
            int idx = base + t + i * 1024;
            if (idx < NE) {
                s[i] = esrc[idx];
                int d = edst[idx];
                b[i] = d >> 8;
                pk[i] = s[i] | ((d & 255) << 16);
                atomicAdd(&hist[b[i]], 1);
            } else {
                b[i] = -1;
            }
        }
        __syncthreads();
        if (t < NB && hist[t] > 0) gbase[t] = atomicAdd(&bcur[t], hist[t]);
        __syncthreads();
#pragma unroll
        for (int i = 0; i < 4; ++i) {
            if (b[i] >= 0) {
                int r = atomicAdd(&lcur[b[i]], 1);
                bpk[b[i] * BCAP + gbase[b[i]] + r] = pk[i];
            }
        }
    } else {
        int t = (blockIdx.x - P1B) * 1024 + threadIdx.x;
        if (t < 128 * 128) {            // WiT[n][k] = Wi[k][n]
            int k = t >> 7, n = t & 127;
            WiT[n * 128 + k] = (h16)Wi[t];
        } else {                        // WoT[n][k] = Wo[k][n]
            int t2 = t - 128 * 128;     // < 8192
            int k = t2 >> 6, n = t2 & 63;
            WoT[n * 128 + k] = (h16)Wo[t2];
        }
    }
}

// Pass 2: per-bucket counting sort -> coalesced csrc, off/deg/dinv.
__global__ __launch_bounds__(256) void k_sort_dinv(
    const int* __restrict__ bpk, const int* __restrict__ bcur,
    int* __restrict__ gcur, int* __restrict__ off, int* __restrict__ degn,
    float* __restrict__ dinv, int* __restrict__ csrc) {
    __shared__ int hist[256], lofs[256], exc[256], lcur[256];
    __shared__ int sgbase;
    int b = blockIdx.x, t = threadIdx.x;
    hist[t] = 0; lcur[t] = 0;
    __syncthreads();
    int cnt = bcur[b];
    if (t == 0) sgbase = atomicAdd(gcur, cnt);
    const int* bp = bpk + b * BCAP;
    for (int j = t; j < cnt; j += 256)
        atomicAdd(&hist[(bp[j] >> 16) & 255], 1);
    __syncthreads();
    lofs[t] = hist[t];
    __syncthreads();
#pragma unroll
    for (int d = 1; d < 256; d <<= 1) {
        int add = (t >= d) ? lofs[t - d] : 0;
        __syncthreads();
        lofs[t] += add;
        __syncthreads();
    }
    exc[t] = lofs[t] - hist[t];
    __syncthreads();
    int gbase = sgbase;
    int node = b * 256 + t;
    if (node < NN) {
        off[node] = gbase + exc[t];
        degn[node] = hist[t];
        dinv[node] = rsqrtf((float)hist[t] + 1.0f);  // +1 self-loop
    }
    __shared__ int scsr[BCAP];
    for (int j = t; j < cnt; j += 256) {
        int p = bp[j];
        int d = (p >> 16) & 255;
        int r = atomicAdd(&lcur[d], 1);
        scsr[exc[d] + r] = p & 0xFFFF;
    }
    __syncthreads();
    for (int j = t; j < cnt; j += 256) csrc[gbase + j] = scsr[j];
}

// MFMA GEMM: out[row][:] = fp16( (A[row][:] @ W) * dinv[row] )
template <int BN, bool AF32>
__global__ __launch_bounds__(256) void k_gemm_mfma(
    const void* __restrict__ Ain, const h16* __restrict__ WT,
    const float* __restrict__ dinv, h16* __restrict__ out) {
    __shared__ h16x8 sXv[64 * 16];
    __shared__ h16x8 sWv[BN * 16];
    char* sX = (char*)sXv;
    char* sW = (char*)sWv;
    const int tid = threadIdx.x;
    const int row0 = blockIdx.x * 64;

#pragma unroll
    for (int i = 0; i < 4; ++i) {
        int c = tid + i * 256;
        int row = c >> 4, kb = c & 15;
        int gr = row0 + row;
        h16x8 v = {};
        if (gr < NN) {
            if (AF32) {
                const float* src = (const float*)Ain + (size_t)gr * 128 + kb * 8;
                float4 u0 = *(const float4*)src;
                float4 u1 = *(const float4*)(src + 4);
                v[0] = (h16)u0.x; v[1] = (h16)u0.y; v[2] = (h16)u0.z; v[3] = (h16)u0.w;
                v[4] = (h16)u1.x; v[5] = (h16)u1.y; v[6] = (h16)u1.z; v[7] = (h16)u1.w;
            } else {
                v = *(const h16x8*)((const h16*)Ain + (size_t)gr * 128 + kb * 8);
            }
        }
        *(h16x8*)(sX + row * 256 + ((kb * 16) ^ ((row & 7) << 4))) = v;
    }
#pragma unroll
    for (int i = 0; i < BN / 16; ++i) {
        int c = tid + i * 256;
        int n = c >> 4, kb = c & 15;
        h16x8 v = *(const h16x8*)&WT[(size_t)n * 128 + kb * 8];
        *(h16x8*)(sW + n * 256 + ((kb * 16) ^ ((n & 7) << 4))) = v;
    }
    __syncthreads();

    const int lane = tid & 63, wv = tid >> 6;
    const int g = lane >> 4, l15 = lane & 15;
    const int r = wv * 16 + l15;
    f32x4 acc[BN / 16];
#pragma unroll
    for (int ct = 0; ct < BN / 16; ++ct) acc[ct] = (f32x4){0.f, 0.f, 0.f, 0.f};

#pragma unroll
    for (int t = 0; t < 4; ++t) {
        int kb2 = t * 64 + g * 16;
        h16x8 a = *(const h16x8*)(sX + r * 256 + (kb2 ^ ((r & 7) << 4)));
#pragma unroll
        for (int ct = 0; ct < BN / 16; ++ct) {
            int n = ct * 16 + l15;
            h16x8 b = *(const h16x8*)(sW + n * 256 + (kb2 ^ ((n & 7) << 4)));
            acc[ct] = __builtin_amdgcn_mfma_f32_16x16x32_f16(a, b, acc[ct], 0, 0, 0);
        }
    }

#pragma unroll
    for (int j = 0; j < 4; ++j) {
        int row = row0 + wv * 16 + g * 4 + j;
        if (row < NN) {
            float dv = dinv[row];
#pragma unroll
            for (int ct = 0; ct < BN / 16; ++ct)
                out[(size_t)row * BN + ct * 16 + l15] = (h16)(acc[ct][j] * dv);
        }
    }
}

// z1[n] = fp16(relu(dinv[n]*(sum h1[src] + h1[n]) + b)); 32-lane group/node.
__global__ __launch_bounds__(256) void k_agg128(
    const h16x4* __restrict__ hs, const float* __restrict__ dinv,
    const int* __restrict__ off, const int* __restrict__ degn,
    const int* __restrict__ csrc,
    const float* __restrict__ bias, h16x4* __restrict__ z) {
    int node = blockIdx.x * 8 + (threadIdx.x >> 5);
    if (node >= NN) return;
    int col = threadIdx.x & 31;
    int s = off[node], e = s + degn[node];
    float a0 = 0.f, a1 = 0.f, a2 = 0.f, a3 = 0.f;
    int j = s;
    for (; j + 8 <= e; j += 8) {
        int i0 = csrc[j],     i1 = csrc[j + 1], i2 = csrc[j + 2], i3 = csrc[j + 3];
        int i4 = csrc[j + 4], i5 = csrc[j + 5], i6 = csrc[j + 6], i7 = csrc[j + 7];
        h16x4 v0 = hs[(size_t)i0 * 32 + col];
        h16x4 v1 = hs[(size_t)i1 * 32 + col];
        h16x4 v2 = hs[(size_t)i2 * 32 + col];
        h16x4 v3 = hs[(size_t)i3 * 32 + col];
        h16x4 v4 = hs[(size_t)i4 * 32 + col];
        h16x4 v5 = hs[(size_t)i5 * 32 + col];
        h16x4 v6 = hs[(size_t)i6 * 32 + col];
        h16x4 v7 = hs[(size_t)i7 * 32 + col];
        a0 += ((float)v0.x + (float)v1.x + (float)v2.x + (float)v3.x) +
              ((float)v4.x + (float)v5.x + (float)v6.x + (float)v7.x);
        a1 += ((float)v0.y + (float)v1.y + (float)v2.y + (float)v3.y) +
              ((float)v4.y + (float)v5.y + (float)v6.y + (float)v7.y);
        a2 += ((float)v0.z + (float)v1.z + (float)v2.z + (float)v3.z) +
              ((float)v4.z + (float)v5.z + (float)v6.z + (float)v7.z);
        a3 += ((float)v0.w + (float)v1.w + (float)v2.w + (float)v3.w) +
              ((float)v4.w + (float)v5.w + (float)v6.w + (float)v7.w);
    }
    for (; j < e; ++j) {
        h16x4 v = hs[(size_t)csrc[j] * 32 + col];
        a0 += (float)v.x; a1 += (float)v.y; a2 += (float)v.z; a3 += (float)v.w;
    }
    h16x4 vs = hs[(size_t)node * 32 + col];  // self loop
    a0 += (float)vs.x; a1 += (float)vs.y; a2 += (float)vs.z; a3 += (float)vs.w;
    float dv = dinv[node];
    float4 bb = ((const float4*)bias)[col];
    float r0 = dv * a0 + bb.x, r1 = dv * a1 + bb.y;
    float r2 = dv * a2 + bb.z, r3 = dv * a3 + bb.w;
    h16x4 o;
    o.x = (h16)(r0 > 0.f ? r0 : 0.f); o.y = (h16)(r1 > 0.f ? r1 : 0.f);
    o.z = (h16)(r2 > 0.f ? r2 : 0.f); o.w = (h16)(r3 > 0.f ? r3 : 0.f);
    z[(size_t)node * 32 + col] = o;
}

// z2[n] = fp16(relu(dinv[n]*(sum h2[src] + h2[n]) + b)); 16-lane group/node.
__global__ __launch_bounds__(256) void k_agg64(
    const h16x4* __restrict__ hs, const float* __restrict__ dinv,
    const int* __restrict__ off, const int* __restrict__ degn,
    const int* __restrict__ csrc,
    const float* __restrict__ bias, h16x4* __restrict__ z) {
    int node = blockIdx.x * 16 + (threadIdx.x >> 4);
    if (node >= NN) return;
    int col = threadIdx.x & 15;
    int s = off[node], e = s + degn[node];
    float a0 = 0.f, a1 = 0.f, a2 = 0.f, a3 = 0.f;
    int j = s;
    for (; j + 8 <= e; j += 8) {
        int i0 = csrc[j],     i1 = csrc[j + 1], i2 = csrc[j + 2], i3 = csrc[j + 3];
        int i4 = csrc[j + 4], i5 = csrc[j + 5], i6 = csrc[j + 6], i7 = csrc[j + 7];
        h16x4 v0 = hs[(size_t)i0 * 16 + col];
        h16x4 v1 = hs[(size_t)i1 * 16 + col];
        h16x4 v2 = hs[(size_t)i2 * 16 + col];
        h16x4 v3 = hs[(size_t)i3 * 16 + col];
        h16x4 v4 = hs[(size_t)i4 * 16 + col];
        h16x4 v5 = hs[(size_t)i5 * 16 + col];
        h16x4 v6 = hs[(size_t)i6 * 16 + col];
        h16x4 v7 = hs[(size_t)i7 * 16 + col];
        a0 += ((float)v0.x + (float)v1.x + (float)v2.x + (float)v3.x) +
              ((float)v4.x + (float)v5.x + (float)v6.x + (float)v7.x);
        a1 += ((float)v0.y + (float)v1.y + (float)v2.y + (float)v3.y) +
              ((float)v4.y + (float)v5.y + (float)v6.y + (float)v7.y);
        a2 += ((float)v0.z + (float)v1.z + (float)v2.z + (float)v3.z) +
              ((float)v4.z + (float)v5.z + (float)v6.z + (float)v7.z);
        a3 += ((float)v0.w + (float)v1.w + (float)v2.w + (float)v3.w) +
              ((float)v4.w + (float)v5.w + (float)v6.w + (float)v7.w);
    }
    for (; j < e; ++j) {
        h16x4 v = hs[(size_t)csrc[j] * 16 + col];
        a0 += (float)v.x; a1 += (float)v.y; a2 += (float)v.z; a3 += (float)v.w;
    }
    h16x4 vs = hs[(size_t)node * 16 + col];  // self loop
    a0 += (float)vs.x; a1 += (float)vs.y; a2 += (float)vs.z; a3 += (float)vs.w;
    float dv = dinv[node];
    float4 bb = ((const float4*)bias)[col];
    float r0 = dv * a0 + bb.x, r1 = dv * a1 + bb.y;
    float r2 = dv * a2 + bb.z, r3 = dv * a3 + bb.w;
    h16x4 o;
    o.x = (h16)(r0 > 0.f ? r0 : 0.f); o.y = (h16)(r1 > 0.f ? r1 : 0.f);
    o.z = (h16)(r2 > 0.f ? r2 : 0.f); o.w = (h16)(r3 > 0.f ? r3 : 0.f);
    z[(size_t)node * 16 + col] = o;
}

// 8-lane groups, h16x8 (16B) loads, 4 pairs/group, 3-step shuffle reduce
__global__ __launch_bounds__(256) void k_dec(const h16* __restrict__ z2,
                                             const int* __restrict__ eli,
                                             float* __restrict__ out) {
    int g = blockIdx.x * 32 + (threadIdx.x >> 3);
    int p0 = g * 4;
    if (p0 >= ND) return;
    int sub = threadIdx.x & 7;
    float v[4];
#pragma unroll
    for (int q = 0; q < 4; ++q) {
        int ia = eli[p0 + q];
        int ib = eli[ND + p0 + q];
        h16x8 va = *(const h16x8*)&z2[(size_t)ia * DO + sub * 8];
        h16x8 vb = *(const h16x8*)&z2[(size_t)ib * DO + sub * 8];
        float acc = 0.f;
#pragma unroll
        for (int k = 0; k < 8; ++k) acc += (float)va[k] * (float)vb[k];
        v[q] = acc;
    }
#pragma unroll
    for (int o = 1; o < 8; o <<= 1) {
#pragma unroll
        for (int q = 0; q < 4; ++q) v[q] += __shfl_xor(v[q], o);
    }
    if (sub == 0) *(float4*)&out[p0] = make_float4(v[0], v[1], v[2], v[3]);
}

extern "C" void kernel_launch(void* const* d_in, const int* in_sizes, int n_in,
                              void* d_out, int out_size, void* d_ws, size_t ws_size,
                              hipStream_t stream) {
    const float* x  = (const float*)d_in[0];
    const float* Wi = (const float*)d_in[1];
    const float* bi = (const float*)d_in[2];
    const float* Wo = (const float*)d_in[3];
    const float* bo = (const float*)d_in[4];
    const int* ei   = (const int*)d_in[5];
    const int* eli  = (const int*)d_in[6];
    float* out = (float*)d_out;

    char* ws = (char*)d_ws;
    size_t o = 0;
    auto alloc = [&](size_t bytes) -> char* {
        char* p = ws + o;
        o = (o + bytes + 255) & ~(size_t)255;
        return p;
    };
    float* dinv = (float*)alloc(NN * 4);
    int* bcur   = (int*)alloc((NB + 1) * 4);   // bcur[NB] = global csrc cursor
    int* off    = (int*)alloc(NN * 4);
    int* degn   = (int*)alloc(NN * 4);
    int* bpk    = (int*)alloc((size_t)NB * BCAP * 4);
    int* csrc   = (int*)alloc((size_t)NE * 4);
    h16* WiT    = (h16*)alloc(128 * 128 * 2);
    h16* WoT    = (h16*)alloc(64 * 128 * 2);
    h16* h1     = (h16*)alloc((size_t)NN * DH * 2);
    h16* z1     = (h16*)alloc((size_t)NN * DH * 2);
    h16* h2     = (h16*)alloc((size_t)NN * DO * 2);
    h16* z2     = (h16*)alloc((size_t)NN * DO * 2);

    const int* esrc = ei;
    const int* edst = ei + NE;

    hipMemsetAsync(bcur, 0, (NB + 1) * 4, stream);
    k_bucket_wt<<<P1B + WTB1, 1024, 0, stream>>>(esrc, edst, bpk, bcur, Wi, Wo, WiT, WoT);
    k_sort_dinv<<<NB, 256, 0, stream>>>(bpk, bcur, &bcur[NB], off, degn, dinv, csrc);

    k_gemm_mfma<DH, true><<<(NN + 63) / 64, 256, 0, stream>>>(x, WiT, dinv, h1);
    k_agg128<<<(NN + 7) / 8, 256, 0, stream>>>((const h16x4*)h1, dinv, off, degn, csrc, bi, (h16x4*)z1);
    k_gemm_mfma<DO, false><<<(NN + 63) / 64, 256, 0, stream>>>(z1, WoT, dinv, h2);
    k_agg64<<<(NN + 15) / 16, 256, 0, stream>>>((const h16x4*)h2, dinv, off, degn, csrc, bo, (h16x4*)z2);

    k_dec<<<(ND + 127) / 128, 256, 0, stream>>>(z2, eli, out);
}